// Round 10
// baseline (341.509 us; speedup 1.0000x reference)
//
#include <hip/hip_runtime.h>
#include <stdint.h>

// ---------------------------------------------------------------------------
// Attention block: out = softmax_causal( rope(xWq) rope(xWk)^T / sqrt(hd) ) (xWv) @ Wo
// B=2 T=2048 D=2048 H=16 KVH=4 hd=128. All fp32 in/out; internal bf16 MFMA.
// Round 6: fuse prep (6 kernels -> 1) and post (3 -> 1); attn micro-opts
// (setprio around MFMA, lazy O-rescale, deferred lrun reduction).
// ---------------------------------------------------------------------------

#define T_SEQ 2048
#define NHEAD 16
#define NKVH  4
#define HD    128
#define BT    4096   // B*T

typedef unsigned short u16;
typedef __attribute__((ext_vector_type(8))) __bf16 bf16x8;
typedef __attribute__((ext_vector_type(8))) u16    u16x8;
typedef __attribute__((ext_vector_type(4))) u16    u16x4;
typedef __attribute__((ext_vector_type(4))) float  f32x4;

// fp32 -> bf16 RNE (finite inputs)
__device__ __forceinline__ u16 f2bf(float f) {
  uint32_t x = __float_as_uint(f);
  return (u16)((x + 0x7FFFu + ((x >> 16) & 1u)) >> 16);
}
__device__ __forceinline__ float bf2f(u16 u) {
  return __uint_as_float(((uint32_t)u) << 16);
}

// async global->LDS, 16B per lane (wave-uniform base + lane*16 dest)
__device__ __forceinline__ void gll16(const void* g, void* l) {
  __builtin_amdgcn_global_load_lds(
      (const __attribute__((address_space(1))) unsigned int*)g,
      (__attribute__((address_space(3))) unsigned int*)l, 16, 0, 0);
}

// ---------------------------------------------------------------------------
// k_prep: fused prep. Block ranges:
//  [0,8192)        cast x -> bf16 (float4/thread)
//  [8192,12288)    wq transpose 2048x2048 -> bf16 [N][K]
//  [12288,16384)   wo transpose 2048x2048
//  [16384,17408)   wk transpose 2048x512
//  [17408,18432)   wv transpose 2048x512
//  [18432,18944)   rope cos/sin tables [T][64]
// ---------------------------------------------------------------------------
__global__ __launch_bounds__(256) void k_prep(const float* __restrict__ x,
                                              const float* __restrict__ wq,
                                              const float* __restrict__ wk,
                                              const float* __restrict__ wv,
                                              const float* __restrict__ wo,
                                              u16* __restrict__ xb,
                                              u16* __restrict__ wqt,
                                              u16* __restrict__ wkt,
                                              u16* __restrict__ wvt,
                                              u16* __restrict__ wot,
                                              float* __restrict__ tc,
                                              float* __restrict__ ts) {
  __shared__ float tile[32][33];
  int blk = blockIdx.x, tid = threadIdx.x;
  if (blk < 8192) {                       // cast x
    size_t id = (size_t)blk * 256 + tid;
    f32x4 v = *reinterpret_cast<const f32x4*>(x + id * 4);
    u16x4 o;
    o[0] = f2bf(v[0]); o[1] = f2bf(v[1]); o[2] = f2bf(v[2]); o[3] = f2bf(v[3]);
    *reinterpret_cast<u16x4*>(xb + id * 4) = o;
    return;
  }
  if (blk >= 18432) {                     // rope tables
    int id = (blk - 18432) * 256 + tid;
    int pos = id >> 6, i = id & 63;
    float freq = exp2f(-(float)i * (13.287712379549449f / 64.0f));
    float ang = (float)pos * freq;
    tc[id] = cosf(ang);
    ts[id] = sinf(ang);
    return;
  }
  // transposes
  const float* src; u16* dst; int C; int g;
  if (blk < 12288)      { src = wq; dst = wqt; C = 2048; g = blk - 8192;
  } else if (blk < 16384){ src = wo; dst = wot; C = 2048; g = blk - 12288;
  } else if (blk < 17408){ src = wk; dst = wkt; C = 512;  g = blk - 16384;
  } else                 { src = wv; dst = wvt; C = 512;  g = blk - 17408; }
  int xt = (C == 2048) ? (g & 63) : (g & 15);
  int yt = (C == 2048) ? (g >> 6) : (g >> 4);
  int c0 = xt * 32, r0 = yt * 32;       // R = 2048 always
  int tx = tid & 31, ty = tid >> 5;     // 32 x 8
#pragma unroll
  for (int i = 0; i < 4; ++i)
    tile[ty + i * 8][tx] = src[(size_t)(r0 + ty + i * 8) * C + c0 + tx];
  __syncthreads();
#pragma unroll
  for (int i = 0; i < 4; ++i)
    dst[(size_t)(c0 + ty + i * 8) * 2048 + r0 + tx] = f2bf(tile[tx][ty + i * 8]);
}

// ---------------------------------------------------------------------------
// k_post: fused RoPE(Q), RoPE(K), V->Vt transpose. Block ranges:
//  [0,4096)      rope Q (scale = 1/sqrt(128))
//  [4096,5120)   rope K (scale = 1)
//  [5120,7168)   transpose V [slice][t][d] -> Vt [slice][d][t]
// ---------------------------------------------------------------------------
__global__ __launch_bounds__(256) void k_post(u16* __restrict__ Qb,
                                              u16* __restrict__ Kb,
                                              const u16* __restrict__ Vb,
                                              u16* __restrict__ Vtb,
                                              const float* __restrict__ tc,
                                              const float* __restrict__ ts) {
  __shared__ u16 vt[32][34];
  int blk = blockIdx.x, tid = threadIdx.x;
  if (blk < 5120) {                       // rope
    u16* buf; int id; float scale;
    if (blk < 4096) { buf = Qb; id = blk * 256 + tid; scale = 0.08838834764831845f; }
    else            { buf = Kb; id = (blk - 4096) * 256 + tid; scale = 1.0f; }
    int i8 = id & 15;
    int t  = (id >> 4) & (T_SEQ - 1);
    int bh = id >> 15;
    u16* p = buf + ((size_t)bh * T_SEQ + t) * HD + i8 * 8;
    u16x8 v = *reinterpret_cast<u16x8*>(p);
    f32x4 c = *reinterpret_cast<const f32x4*>(tc + t * 64 + i8 * 4);
    f32x4 s = *reinterpret_cast<const f32x4*>(ts + t * 64 + i8 * 4);
    u16x8 o;
#pragma unroll
    for (int j = 0; j < 4; ++j) {
      float x1 = bf2f(v[2 * j]), x2 = bf2f(v[2 * j + 1]);
      o[2 * j]     = f2bf((x1 * c[j] - x2 * s[j]) * scale);
      o[2 * j + 1] = f2bf((x1 * s[j] + x2 * c[j]) * scale);
    }
    *reinterpret_cast<u16x8*>(p) = o;
    return;
  }
  // V transpose: g in [0,2048): slice = g&7, d-tile = (g>>3)&3, t-tile = g>>5
  int g = blk - 5120;
  int slice = g & 7, d0 = ((g >> 3) & 3) * 32, t0 = (g >> 5) * 32;
  const u16* src = Vb + (size_t)slice * T_SEQ * HD;
  u16* dst = Vtb + (size_t)slice * HD * T_SEQ;
  int tx = tid & 31, ty = tid >> 5;
#pragma unroll
  for (int i = 0; i < 4; ++i)
    vt[ty + i * 8][tx] = src[(size_t)(t0 + ty + i * 8) * HD + d0 + tx];
  __syncthreads();
#pragma unroll
  for (int i = 0; i < 4; ++i)
    dst[(size_t)(d0 + ty + i * 8) * T_SEQ + t0 + tx] = vt[tx][ty + i * 8];
}

// ---------------------------------------------------------------------------
// m97-structure bf16 GEMM: C[M=4096][N] = A[4096][2048] * W, W given as Wt[N][2048].
// 128x128 tile, BK=32, 4 waves (2x2 of 64x64), global_load_lds staging.
// EPI=0: N=3072 fused QKV, epilogue scatters bf16 into Q/K/V head layouts.
// EPI=1: N=2048, epilogue stores fp32 to Cf.
// ---------------------------------------------------------------------------
template <int EPI>
__global__ __launch_bounds__(256) void k_gemm(const u16* __restrict__ A,
                                              const u16* __restrict__ W0,
                                              const u16* __restrict__ W1,
                                              const u16* __restrict__ W2,
                                              u16* __restrict__ Qb,
                                              u16* __restrict__ Kb,
                                              u16* __restrict__ Vb,
                                              float* __restrict__ Cf) {
  __shared__ u16 As[128 * 32];
  __shared__ u16 Bs[128 * 32];
  int t = threadIdx.x;
  int bx = blockIdx.x, by = blockIdx.y;
  int ncol0 = bx * 128;
  const u16* Bt;
  if (EPI == 0) {
    if (ncol0 < 2048)      Bt = W0 + (size_t)ncol0 * 2048;
    else if (ncol0 < 2560) Bt = W1 + (size_t)(ncol0 - 2048) * 2048;
    else                   Bt = W2 + (size_t)(ncol0 - 2560) * 2048;
  } else {
    Bt = W0 + (size_t)ncol0 * 2048;
  }
  const u16* ga = A  + (size_t)(by * 128 + (t >> 2)) * 2048 + (t & 3) * 8;
  const u16* gb = Bt + (size_t)(t >> 2) * 2048 + (t & 3) * 8;
  int w = t >> 6, l = t & 63;
  int wr = w >> 1, wc = w & 1;
  int lr = l & 15, lh = l >> 4;
  f32x4 acc[4][4] = {};
  for (int kb = 0; kb < 2048; kb += 32) {
    __syncthreads();
    gll16(ga,             &As[t * 8]);
    gll16(ga + 64 * 2048, &As[2048 + t * 8]);
    gll16(gb,             &Bs[t * 8]);
    gll16(gb + 64 * 2048, &Bs[2048 + t * 8]);
    ga += 32; gb += 32;
    __syncthreads();
    bf16x8 af[4], bw[4];
#pragma unroll
    for (int fr = 0; fr < 4; ++fr)
      af[fr] = *reinterpret_cast<const bf16x8*>(&As[(wr * 64 + fr * 16 + lr) * 32 + lh * 8]);
#pragma unroll
    for (int fc = 0; fc < 4; ++fc)
      bw[fc] = *reinterpret_cast<const bf16x8*>(&Bs[(wc * 64 + fc * 16 + lr) * 32 + lh * 8]);
#pragma unroll
    for (int fr = 0; fr < 4; ++fr)
#pragma unroll
      for (int fc = 0; fc < 4; ++fc)
        acc[fr][fc] = __builtin_amdgcn_mfma_f32_16x16x32_bf16(af[fr], bw[fc], acc[fr][fc], 0, 0, 0);
  }
  int row0 = by * 128 + wr * 64;
  int col0 = ncol0 + wc * 64;
#pragma unroll
  for (int fr = 0; fr < 4; ++fr)
#pragma unroll
    for (int fc = 0; fc < 4; ++fc)
#pragma unroll
      for (int r = 0; r < 4; ++r) {
        int row = row0 + fr * 16 + lh * 4 + r;   // C/D: row=(l>>4)*4+reg, col=l&15
        int col = col0 + fc * 16 + lr;
        float v = acc[fr][fc][r];
        if (EPI == 1) {
          Cf[(size_t)row * 2048 + col] = v;
        } else {
          int b = row >> 11, tt = row & 2047;
          if (col < 2048) {
            int h = col >> 7, d = col & 127;
            Qb[((size_t)(b * NHEAD + h) * T_SEQ + tt) * HD + d] = f2bf(v);
          } else if (col < 2560) {
            int c2 = col - 2048; int h = c2 >> 7, d = c2 & 127;
            Kb[((size_t)(b * NKVH + h) * T_SEQ + tt) * HD + d] = f2bf(v);
          } else {
            int c2 = col - 2560; int h = c2 >> 7, d = c2 & 127;
            Vb[((size_t)(b * NKVH + h) * T_SEQ + tt) * HD + d] = f2bf(v);
          }
        }
      }
}

// ---------------------------------------------------------------------------
// Flash attention v3.1 (round 6): r5 structure + micro-opts:
//   * s_setprio(1) around QK / PV MFMA clusters (T5, +4-7% per m191)
//   * per-lane partial lrun, ONE end-of-loop shuffle reduction (-16 shfl/tile)
//   * lazy O-rescale: skip 32 muls when no row max grew (exp(0)==1 exact)
// Structure unchanged: 512 blocks x 8 waves, LDS-staged K (dbuf) + V,
// XOR-swizzled, XCD-pinned slices, level-paired balance, 2 barriers/tile.
// ---------------------------------------------------------------------------
__global__ __launch_bounds__(512, 4) void k_attn(const u16* __restrict__ Q,
                                                 const u16* __restrict__ K,
                                                 const u16* __restrict__ Vt,
                                                 u16* __restrict__ O) {
  __shared__ u16 KbS[2][64 * 128];   // 2 x 16KB, rows 256B
  __shared__ u16 VbS[128 * 64];      // 16KB, rows 128B ([d][t] tile)
  __shared__ u16 Plds[8][16][72];    // per-wave P roundtrip, stride 144B

  int blk   = blockIdx.x;            // 0..511
  int slice = blk & 7;               // b*4+kvh (XCD-pinned: blk%8)
  int half  = (blk >> 3) & 1;
  int g     = blk >> 4;              // 0..31
  int lvl   = (g < 16) ? g : 47 - g; // pair levels L and 31-L across the grid
  int nt    = 32 - lvl;              // KV-64 tiles for this block (uniform!)
  int w = threadIdx.x >> 6, l = threadIdx.x & 63;
  int lr = l & 15, lh = l >> 4;
  int hg = w & 3, q4 = half * 2 + (w >> 2);
  int qrow0 = ((nt - 1) * 4 + q4) * 16;
  int b = slice >> 2, kvh = slice & 3, h = kvh * 4 + hg;

  const u16* Qp = Q  + ((size_t)(b * NHEAD + h) * T_SEQ) * HD;
  const u16* Kp = K  + ((size_t)(b * NKVH + kvh) * T_SEQ) * HD;
  const u16* Vp = Vt + ((size_t)(b * NKVH + kvh) * HD) * T_SEQ;  // [d][t]

  bf16x8 qf[4];
#pragma unroll
  for (int ks = 0; ks < 4; ++ks)
    qf[ks] = *reinterpret_cast<const bf16x8*>(Qp + (size_t)(qrow0 + lr) * HD + ks * 32 + lh * 8);

  f32x4 o[8] = {};
  float mrun[4], lrun[4];
#pragma unroll
  for (int r = 0; r < 4; ++r) { mrun[r] = -1e30f; lrun[r] = 0.f; }

  int kx = (lr & 7) << 4;  // XOR swizzle key (bits 6:4), row&7 == lr&7

  // ---- prologue: stage K tile 0 into KbS[0] ----
#pragma unroll
  for (int i = 0; i < 2; ++i) {
    int L = (w * 2 + i) * 1024 + l * 16;          // physical LDS byte offset
    int P = L ^ (((L >> 8) & 7) << 4);            // logical byte offset (row=P>>8)
    gll16((const char*)Kp + P, (char*)KbS[0] + L);
  }
  __syncthreads();

  int cur = 0;
  for (int it = 0; it < nt; ++it) {
    int t0 = it * 64;
    // ---- stage V(it) + K(it+1): issued now, consumed a phase later ----
#pragma unroll
    for (int i = 0; i < 2; ++i) {
      int L = (w * 2 + i) * 1024 + l * 16;
      int P = L ^ (((L >> 7) & 7) << 4);          // V rows are 128B (row=P>>7)
      int d = P >> 7, tb = P & 127;
      gll16((const char*)(Vp + t0) + (size_t)d * (T_SEQ * 2) + tb, (char*)VbS + L);
    }
    if (it + 1 < nt) {
#pragma unroll
      for (int i = 0; i < 2; ++i) {
        int L = (w * 2 + i) * 1024 + l * 16;
        int P = L ^ (((L >> 8) & 7) << 4);
        gll16((const char*)Kp + (size_t)(t0 + 64) * 256 + P, (char*)KbS[cur ^ 1] + L);
      }
    }
    // ---- S = Q K^T from swizzled LDS ----
    const char* kb = (const char*)KbS[cur];
    f32x4 s[4] = {};
#pragma unroll
    for (int ct = 0; ct < 4; ++ct) {
      bf16x8 kf[4];
#pragma unroll
      for (int ks = 0; ks < 4; ++ks)
        kf[ks] = *reinterpret_cast<const bf16x8*>(
            kb + ct * 4096 + lr * 256 + ((ks * 64 + lh * 16) ^ kx));
      __builtin_amdgcn_s_setprio(1);
#pragma unroll
      for (int ks = 0; ks < 4; ++ks)
        s[ct] = __builtin_amdgcn_mfma_f32_16x16x32_bf16(qf[ks], kf[ks], s[ct], 0, 0, 0);
      __builtin_amdgcn_s_setprio(0);
    }
    // causal mask only on the final (diagonal) tile
    if (it == nt - 1) {
#pragma unroll
      for (int ct = 0; ct < 4; ++ct) {
        int tcol = t0 + ct * 16 + lr;
#pragma unroll
        for (int r = 0; r < 4; ++r)
          if (tcol > qrow0 + lh * 4 + r) s[ct][r] = -1e30f;
      }
    }
    // ---- online softmax; lrun kept as per-lane partial ----
    float fs[4], rsum[4];
    bool grow = false;
#pragma unroll
    for (int r = 0; r < 4; ++r) {
      float rm = fmaxf(fmaxf(s[0][r], s[1][r]), fmaxf(s[2][r], s[3][r]));
      rm = fmaxf(rm, __shfl_xor(rm, 1));
      rm = fmaxf(rm, __shfl_xor(rm, 2));
      rm = fmaxf(rm, __shfl_xor(rm, 4));
      rm = fmaxf(rm, __shfl_xor(rm, 8));
      float nm = fmaxf(mrun[r], rm);
      grow = grow || (nm > mrun[r]);
      fs[r] = __expf(mrun[r] - nm);
      mrun[r] = nm;
      float rs = 0.f;
#pragma unroll
      for (int ct = 0; ct < 4; ++ct) {
        float p = __expf(s[ct][r] - nm);
        s[ct][r] = p;
        rs += p;
      }
      rsum[r] = rs;
    }
    if (__any(grow)) {
#pragma unroll
      for (int r = 0; r < 4; ++r) {
        lrun[r] = lrun[r] * fs[r] + rsum[r];
#pragma unroll
        for (int cd = 0; cd < 8; ++cd) o[cd][r] *= fs[r];
      }
    } else {
#pragma unroll
      for (int r = 0; r < 4; ++r) lrun[r] += rsum[r];
    }
    // ---- P (C-layout) -> bf16 LDS -> A-layout fragments (wave-private) ----
#pragma unroll
    for (int ct = 0; ct < 4; ++ct)
#pragma unroll
      for (int r = 0; r < 4; ++r)
        Plds[w][lh * 4 + r][ct * 16 + lr] = f2bf(s[ct][r]);
    bf16x8 pf[2];
#pragma unroll
    for (int ks = 0; ks < 2; ++ks)
      pf[ks] = *reinterpret_cast<const bf16x8*>(&Plds[w][lr][ks * 32 + lh * 8]);

    __syncthreads();  // V(it) staged & visible (loads issued a phase ago)

    // ---- O += P V from swizzled LDS ----
    const char* vb = (const char*)VbS;
#pragma unroll
    for (int cd = 0; cd < 8; ++cd) {
      bf16x8 vf0 = *reinterpret_cast<const bf16x8*>(
          vb + cd * 2048 + lr * 128 + ((0 * 64 + lh * 16) ^ kx));
      bf16x8 vf1 = *reinterpret_cast<const bf16x8*>(
          vb + cd * 2048 + lr * 128 + ((1 * 64 + lh * 16) ^ kx));
      __builtin_amdgcn_s_setprio(1);
      o[cd] = __builtin_amdgcn_mfma_f32_16x16x32_bf16(pf[0], vf0, o[cd], 0, 0, 0);
      o[cd] = __builtin_amdgcn_mfma_f32_16x16x32_bf16(pf[1], vf1, o[cd], 0, 0, 0);
      __builtin_amdgcn_s_setprio(0);
    }
    __syncthreads();  // all reads of VbS/KbS[cur] done; K(it+1) visible
    cur ^= 1;
  }
  // deferred lrun reduction (once instead of per-tile)
  float inv[4];
#pragma unroll
  for (int r = 0; r < 4; ++r) {
    float tsum = lrun[r];
    tsum += __shfl_xor(tsum, 1);
    tsum += __shfl_xor(tsum, 2);
    tsum += __shfl_xor(tsum, 4);
    tsum += __shfl_xor(tsum, 8);
    inv[r] = 1.0f / tsum;
  }
#pragma unroll
  for (int cd = 0; cd < 8; ++cd)
#pragma unroll
    for (int r = 0; r < 4; ++r) {
      int row = qrow0 + lh * 4 + r;
      int col = h * HD + cd * 16 + lr;
      O[((size_t)(b * T_SEQ + row)) * 2048 + col] = f2bf(o[cd][r] * inv[r]);
    }
}

// ---------------------------------------------------------------------------
extern "C" void kernel_launch(void* const* d_in, const int* in_sizes, int n_in,
                              void* d_out, int out_size, void* d_ws, size_t ws_size,
                              hipStream_t stream) {
  const float* x  = (const float*)d_in[0];
  const float* wq = (const float*)d_in[1];
  const float* wk = (const float*)d_in[2];
  const float* wv = (const float*)d_in[3];
  const float* wo = (const float*)d_in[4];
  float* out = (float*)d_out;

  char* ws = (char*)d_ws;
  size_t off = 0;
  auto alloc = [&](size_t bytes) {
    char* p = ws + off;
    off = (off + bytes + 255) & ~(size_t)255;
    return p;
  };
  u16* xb   = (u16*)alloc((size_t)BT * 2048 * 2);          // 16.8 MB (reused as Ob)
  u16* wqt  = (u16*)alloc((size_t)2048 * 2048 * 2);        //  8.4 MB
  u16* wkt  = (u16*)alloc((size_t)512 * 2048 * 2);         //  2.1 MB
  u16* wvt  = (u16*)alloc((size_t)512 * 2048 * 2);         //  2.1 MB
  u16* wot  = (u16*)alloc((size_t)2048 * 2048 * 2);        //  8.4 MB
  u16* Qb   = (u16*)alloc((size_t)BT * 2048 * 2);          // 16.8 MB
  u16* Kb   = (u16*)alloc((size_t)2 * NKVH * T_SEQ * HD * 2);  // 4.2 MB
  u16* Vb   = (u16*)alloc((size_t)2 * NKVH * T_SEQ * HD * 2);  // 4.2 MB
  u16* Vtb  = (u16*)alloc((size_t)2 * NKVH * T_SEQ * HD * 2);  // 4.2 MB
  float* tabc = (float*)alloc((size_t)T_SEQ * 64 * 4);     // 0.5 MB
  float* tabs = (float*)alloc((size_t)T_SEQ * 64 * 4);     // 0.5 MB
  u16* Ob = xb;  // xb dead after gemm<0>; reuse for attention output
  (void)in_sizes; (void)n_in; (void)out_size; (void)ws_size;

  // fused prep: cast_x + 4 weight transposes + rope tables (1 launch)
  k_prep<<<dim3(18944), dim3(256), 0, stream>>>(x, wq, wk, wv, wo,
                                                xb, wqt, wkt, wvt, wot,
                                                tabc, tabs);
  // QKV projection (fused N=3072)
  k_gemm<0><<<dim3(24, 32), dim3(256), 0, stream>>>(xb, wqt, wkt, wvt, Qb, Kb, Vb, nullptr);
  // fused post: RoPE(Q,K) + V->Vt (1 launch)
  k_post<<<dim3(7168), dim3(256), 0, stream>>>(Qb, Kb, Vb, Vtb, tabc, tabs);
  // attention: 512 blocks x 8 waves, LDS-staged K/V, XCD-pinned, level-paired
  k_attn<<<dim3(512), dim3(512), 0, stream>>>(Qb, Kb, Vtb, Ob);
  // output projection (fp32 out)
  k_gemm<1><<<dim3(16, 32), dim3(256), 0, stream>>>(Ob, wot, nullptr, nullptr,
                                                    nullptr, nullptr, nullptr, out);
}